// Round 13
// baseline (322.604 us; speedup 1.0000x reference)
//
#include <hip/hip_runtime.h>
#include <cstdint>

constexpr int B_   = 16;
constexpr int CIN  = 128;
constexpr int H_   = 224;
constexpr int W_   = 224;
constexpr int COUT = 256;
constexpr int HOUT = 112;
constexpr int WOUT = 75;

constexpr int CI_SC = 16;     // input channels per super-chunk
constexpr int KSC_R = 144;    // real k per super-chunk
constexpr int KP    = 160;    // padded k per super-chunk (5 x K=32)
constexpr int NSC   = 8;
constexpr int THREADS = 256;  // 4 waves: 4 co-groups of 64

constexpr int WS_SH8  = COUT * KP * NSC / 8;       // 40960 short8 slots
constexpr size_t WS_NEED = (size_t)WS_SH8 * 16;    // 655360 B

constexpr int ABUF  = 25600;                       // one A tile (bytes)
constexpr int LDS_TOT = 2 * ABUF;                  // double-buffered A

typedef float  f32x4   __attribute__((ext_vector_type(4)));
typedef short  short8  __attribute__((ext_vector_type(8)));

struct U64x2 { unsigned long long lo, hi; };
__device__ inline short8 bc8(unsigned long long a, unsigned long long b) {
  U64x2 u{a, b};
  return __builtin_bit_cast(short8, u);
}

__device__ inline unsigned cvtpk(float a, float b) {
  unsigned r;
  asm("v_cvt_pk_bf16_f32 %0, %1, %2" : "=v"(r) : "v"(a), "v"(b));
  return r;  // lo16 = bf16(a), hi16 = bf16(b)
}

// ---- prepass: fp32 weights -> bf16, layout [sc][kc][g][co][8k] (coalesced B frags) ----
__global__ __launch_bounds__(256) void wprep(const float* __restrict__ wgt,
                                             uint4* __restrict__ ws) {
  int o  = blockIdx.x * 256 + threadIdx.x;   // 40960 short8 outputs
  int co = o & 255;
  int t  = o >> 8;          // 0..159
  int g  = t & 3;
  int u  = t >> 2;          // 0..39
  int kc = u % 5;
  int sc = u / 5;
  int kloc = kc * 32 + g * 8;                // k within super-chunk
  float f[8];
  if (kloc < KSC_R) {
    const float* p = wgt + (size_t)co * 1152 + sc * KSC_R + kloc;  // 8-aligned
    float4 a = *(const float4*)p;
    float4 b = *(const float4*)(p + 4);
    f[0] = a.x; f[1] = a.y; f[2] = a.z; f[3] = a.w;
    f[4] = b.x; f[5] = b.y; f[6] = b.z; f[7] = b.w;
  } else {
#pragma unroll
    for (int e = 0; e < 8; ++e) f[e] = 0.f;
  }
  ws[o] = uint4{cvtpk(f[0], f[1]), cvtpk(f[2], f[3]), cvtpk(f[4], f[5]), cvtpk(f[6], f[7])};
}

// fallback (no ws): convert from fp32 weights in-flight (uncoalesced, slow but correct)
__device__ __forceinline__ short8 load_bq(const float* q, int kc, int g) {
  if (kc == 4 && g >= 2) return short8{};
  const float* s = q + kc * 32;
  float4 x0 = *(const float4*)s, x1 = *(const float4*)(s + 4);
  uint4 u{cvtpk(x0.x, x0.y), cvtpk(x0.z, x0.w), cvtpk(x1.x, x1.y), cvtpk(x1.z, x1.w)};
  return __builtin_bit_cast(short8, u);
}

// 10 tr reads for one K=32 chunk (5 m-frags x 2 k-halves); A row (4k x 80m) = 640B
#define TR_ISSUE(S, KC, BUFO)                                                             \
  {                                                                                       \
    unsigned a_ = abase + (BUFO) + (unsigned)((KC) * 5120);                               \
    asm volatile("ds_read_b64_tr_b16 %0, %1"             : "=v"(S##0) : "v"(a_));         \
    asm volatile("ds_read_b64_tr_b16 %0, %1 offset:640"  : "=v"(S##1) : "v"(a_));         \
    asm volatile("ds_read_b64_tr_b16 %0, %1 offset:128"  : "=v"(S##2) : "v"(a_));         \
    asm volatile("ds_read_b64_tr_b16 %0, %1 offset:768"  : "=v"(S##3) : "v"(a_));         \
    asm volatile("ds_read_b64_tr_b16 %0, %1 offset:256"  : "=v"(S##4) : "v"(a_));         \
    asm volatile("ds_read_b64_tr_b16 %0, %1 offset:896"  : "=v"(S##5) : "v"(a_));         \
    asm volatile("ds_read_b64_tr_b16 %0, %1 offset:384"  : "=v"(S##6) : "v"(a_));         \
    asm volatile("ds_read_b64_tr_b16 %0, %1 offset:1024" : "=v"(S##7) : "v"(a_));         \
    asm volatile("ds_read_b64_tr_b16 %0, %1 offset:512"  : "=v"(S##8) : "v"(a_));         \
    asm volatile("ds_read_b64_tr_b16 %0, %1 offset:1152" : "=v"(S##9) : "v"(a_));         \
  }

// B frags into named registers (plain C++ loads -> compiler-managed vmcnt, spill-proof)
#define BLOADR(X, P, KC)                                                                  \
  X##0 = (P)[(KC) * 1024];                                                                \
  X##1 = (P)[(KC) * 1024 + 16];                                                           \
  X##2 = (P)[(KC) * 1024 + 32];                                                           \
  X##3 = (P)[(KC) * 1024 + 48];

// WAITLG counts DS ops only (tr reads + our ds_writes) — spills are VMEM, never
// perturb this counter. (Round-10/11 lesson: manual vmcnt ledgers are fragile;
// lgkm-only ledgers are exact.)
#define WAITLG(N)                                                                         \
  asm volatile("s_waitcnt lgkmcnt(" #N ")" ::: "memory");                                 \
  __builtin_amdgcn_sched_barrier(0);

// 5 A-frags x 4 B-frags = 20 MFMAs
#define MFMA_SET(S, B0, B1, B2, B3)                                                       \
  {                                                                                       \
    short8 a0_ = bc8(S##0, S##1);                                                         \
    short8 a1_ = bc8(S##2, S##3);                                                         \
    short8 a2_ = bc8(S##4, S##5);                                                         \
    short8 a3_ = bc8(S##6, S##7);                                                         \
    short8 a4_ = bc8(S##8, S##9);                                                         \
    __builtin_amdgcn_s_setprio(1);                                                        \
    acc[0][0] = __builtin_amdgcn_mfma_f32_16x16x32_bf16(a0_, B0, acc[0][0], 0, 0, 0);     \
    acc[0][1] = __builtin_amdgcn_mfma_f32_16x16x32_bf16(a0_, B1, acc[0][1], 0, 0, 0);     \
    acc[0][2] = __builtin_amdgcn_mfma_f32_16x16x32_bf16(a0_, B2, acc[0][2], 0, 0, 0);     \
    acc[0][3] = __builtin_amdgcn_mfma_f32_16x16x32_bf16(a0_, B3, acc[0][3], 0, 0, 0);     \
    acc[1][0] = __builtin_amdgcn_mfma_f32_16x16x32_bf16(a1_, B0, acc[1][0], 0, 0, 0);     \
    acc[1][1] = __builtin_amdgcn_mfma_f32_16x16x32_bf16(a1_, B1, acc[1][1], 0, 0, 0);     \
    acc[1][2] = __builtin_amdgcn_mfma_f32_16x16x32_bf16(a1_, B2, acc[1][2], 0, 0, 0);     \
    acc[1][3] = __builtin_amdgcn_mfma_f32_16x16x32_bf16(a1_, B3, acc[1][3], 0, 0, 0);     \
    acc[2][0] = __builtin_amdgcn_mfma_f32_16x16x32_bf16(a2_, B0, acc[2][0], 0, 0, 0);     \
    acc[2][1] = __builtin_amdgcn_mfma_f32_16x16x32_bf16(a2_, B1, acc[2][1], 0, 0, 0);     \
    acc[2][2] = __builtin_amdgcn_mfma_f32_16x16x32_bf16(a2_, B2, acc[2][2], 0, 0, 0);     \
    acc[2][3] = __builtin_amdgcn_mfma_f32_16x16x32_bf16(a2_, B3, acc[2][3], 0, 0, 0);     \
    acc[3][0] = __builtin_amdgcn_mfma_f32_16x16x32_bf16(a3_, B0, acc[3][0], 0, 0, 0);     \
    acc[3][1] = __builtin_amdgcn_mfma_f32_16x16x32_bf16(a3_, B1, acc[3][1], 0, 0, 0);     \
    acc[3][2] = __builtin_amdgcn_mfma_f32_16x16x32_bf16(a3_, B2, acc[3][2], 0, 0, 0);     \
    acc[3][3] = __builtin_amdgcn_mfma_f32_16x16x32_bf16(a3_, B3, acc[3][3], 0, 0, 0);     \
    acc[4][0] = __builtin_amdgcn_mfma_f32_16x16x32_bf16(a4_, B0, acc[4][0], 0, 0, 0);     \
    acc[4][1] = __builtin_amdgcn_mfma_f32_16x16x32_bf16(a4_, B1, acc[4][1], 0, 0, 0);     \
    acc[4][2] = __builtin_amdgcn_mfma_f32_16x16x32_bf16(a4_, B2, acc[4][2], 0, 0, 0);     \
    acc[4][3] = __builtin_amdgcn_mfma_f32_16x16x32_bf16(a4_, B3, acc[4][3], 0, 0, 0);     \
    __builtin_amdgcn_s_setprio(0);                                                        \
  }

// T14: issue sc's x loads (items j=0..2, 12 loads/thread) into regs; plain C++,
// compiler-managed waits.
#define STAGE_LOAD(SC)                                                                    \
  {                                                                                       \
    const float* xs_ = xb + (size_t)((SC) & 7) * (CI_SC * H_ * W_);                       \
    _Pragma("unroll")                                                                     \
    for (int j = 0; j < 3; ++j) {                                                         \
      int it  = tid + THREADS * j;                                                        \
      int gg  = it % 19;                                                                  \
      int rid = it / 19;                                                                  \
      int ci  = rid & 15;                                                                 \
      int kh  = rid >> 4;                                                                 \
      int ih  = 2 * oh - 1 + kh;                                                          \
      bool rowok = (unsigned)ih < (unsigned)H_;                                           \
      int ro  = (ci * H_ + (rowok ? ih : 0)) * W_;                                        \
      int iwb = 12 * gg;                                                                  \
      const float* ap = xs_ + (ro + iwb);                                                 \
      pa[j] = *(const float4*)ap;                                                         \
      pb[j] = *(const float4*)(ap + 4);                                                   \
      pc[j] = *(const float4*)(xs_ + (ro + (iwb + 8 > 220 ? 220 : iwb + 8)));             \
      pm[j] = xs_[ro + iwb - (gg ? 1 : 0)];                                               \
    }                                                                                     \
  }

// stage-write sc SCW into buffer at byte offset BUFO (j=0..2 from regs, j=3 inline)
#define STAGE_WRITE(SCW, BUFO)                                                            \
  {                                                                                       \
    const float* xsw = xb + (size_t)((SCW) & 7) * (CI_SC * H_ * W_);                      \
    _Pragma("unroll")                                                                     \
    for (int j = 0; j < 4; ++j) {                                                         \
      int it = tid + THREADS * j;                                                         \
      if (j < 3 || it < 912) {                                                            \
        int gg  = it % 19;                                                                \
        int rid = it / 19;                                                                \
        int ci  = rid & 15;                                                               \
        int kh  = rid >> 4;                                                               \
        int ih  = 2 * oh - 1 + kh;                                                        \
        bool rowok = (unsigned)ih < (unsigned)H_;                                         \
        unsigned mAj = rowok ? 0xFFFFFFFFu : 0u;                                          \
        unsigned mFj = mAj & (gg ? 0xFFFFFFFFu : 0xFFFF0000u);                            \
        float4 a4, b4, c4;                                                                \
        float fm1;                                                                        \
        if (j < 3) {                                                                      \
          a4 = pa[j]; b4 = pb[j]; c4 = pc[j]; fm1 = pm[j];                                \
        } else {                                                                          \
          int ro  = (ci * H_ + (rowok ? ih : 0)) * W_;                                    \
          int iwb = 12 * gg;                                                              \
          const float* ap = xsw + (ro + iwb);                                             \
          a4 = *(const float4*)ap;                                                        \
          b4 = *(const float4*)(ap + 4);                                                  \
          c4 = *(const float4*)(xsw + (ro + (iwb + 8 > 220 ? 220 : iwb + 8)));            \
          fm1 = xsw[ro + iwb - (gg ? 1 : 0)];                                             \
        }                                                                                 \
        int k = ci * 9 + kh * 3;                                                          \
        int m = 4 * gg;                                                                   \
        unsigned base = (unsigned)(((k >> 2) * 5 + (m >> 4)) * 128 + (m & 15) * 2) + (BUFO); \
        unsigned o0 = base + (unsigned)((k & 3) * 32);                                    \
        unsigned o1 = base + (unsigned)(((k + 1) & 3) * 32) + (((k + 1) >> 2) - (k >> 2)) * 640u; \
        unsigned o2 = base + (unsigned)(((k + 2) & 3) * 32) + (((k + 2) >> 2) - (k >> 2)) * 640u; \
        unsigned l0 = cvtpk(fm1,  a4.z) & mFj;                                            \
        unsigned h0 = cvtpk(b4.y, c4.x) & mAj;                                            \
        unsigned l1 = cvtpk(a4.x, a4.w) & mAj;                                            \
        unsigned h1 = cvtpk(b4.z, c4.y) & mAj;                                            \
        unsigned l2 = cvtpk(a4.y, b4.x) & mAj;                                            \
        unsigned h2 = cvtpk(b4.w, c4.z) & mAj;                                            \
        *(uint2*)&smem[o0] = make_uint2(l0, h0);                                          \
        *(uint2*)&smem[o1] = make_uint2(l1, h1);                                          \
        *(uint2*)&smem[o2] = make_uint2(l2, h2);                                          \
      }                                                                                   \
    }                                                                                     \
  }

template <int WS>
__global__ __launch_bounds__(THREADS, 2) void conv_mfma(
    const float* __restrict__ x, const float* __restrict__ wgt,
    const short8* __restrict__ wbf, const float* __restrict__ bias,
    float* __restrict__ out) {

  // A tile, DOUBLE-buffered: 2 x [KP=160 k][80 m] bf16, [4k x 16m] subtiles:
  // byte(k,m) = ((k>>2)*5 + (m>>4))*128 + (k&3)*32 + (m&15)*2   (25600 B each)
  __shared__ __align__(16) unsigned char smem[LDS_TOT];

  // XCD-chunked bijective swizzle: 1792 blocks = 8 XCDs * 224
  int Lid = (blockIdx.x & 7) * 224 + (blockIdx.x >> 3);
  int oh  = Lid % 112;
  int b   = Lid / 112;

  const int tid   = threadIdx.x;
  const int lane  = tid & 63;
  const int cogrp = tid >> 6;         // wave id = co-group of 64
  const int g     = lane >> 4;        // k-lane-group
  const int l15   = lane & 15;

  const float* xb = x + (size_t)b * CIN * H_ * W_;
  const int coB_  = cogrp * 64 + l15;

  const unsigned sbase = (unsigned)(uintptr_t)&smem[0];
  const unsigned abase = sbase + (unsigned)(g * 1280 + l15 * 8);

  // NaN fix: zero never-staged A k-rows 144..159 in BOTH buffers (2560 B @23040 each).
  if (tid < 160) {
    *reinterpret_cast<uint4*>(&smem[23040 + tid * 16])        = uint4{0u, 0u, 0u, 0u};
    *reinterpret_cast<uint4*>(&smem[ABUF + 23040 + tid * 16]) = uint4{0u, 0u, 0u, 0u};
  }

  f32x4 acc[5][4];
#pragma unroll
  for (int mf = 0; mf < 5; ++mf)
#pragma unroll
    for (int cf = 0; cf < 4; ++cf)
#pragma unroll
      for (int i = 0; i < 4; ++i) acc[mf][cf][i] = 0.f;

  unsigned long long tA0, tA1, tA2, tA3, tA4, tA5, tA6, tA7, tA8, tA9;
  unsigned long long tB0, tB1, tB2, tB3, tB4, tB5, tB6, tB7, tB8, tB9;
  short8 bX0, bX1, bX2, bX3, bY0, bY1, bY2, bY3, bZ0, bZ1, bZ2, bZ3;
  float4 pa[3], pb[3], pc[3];
  float  pm[3];

  // ---- prologue: stage sc0 into buf0; prefetch sc1 x; prefetch sc0 kc0/kc1 B ----
  STAGE_LOAD(0);
  STAGE_WRITE(0, 0u);
  if (WS) {
    const short8* w0 = wbf + g * 256 + cogrp * 64 + l15;
    BLOADR(bX, w0, 0)
    BLOADR(bY, w0, 1)
  }
  __syncthreads();
  STAGE_LOAD(1);

  for (int sc = 0; sc < NSC; ++sc) {
    const unsigned bufo  = (unsigned)((sc & 1) * ABUF);
    const unsigned nbufo = bufo ^ (unsigned)ABUF;

    if (WS) {
      const short8* wsb  = wbf + (size_t)sc * 5120 + g * 256 + cogrp * 64 + l15;
      const short8* wsbn = wbf + (size_t)((sc + 1) & 7) * 5120 + g * 256 + cogrp * 64 + l15;

      TR_ISSUE(tA, 0, bufo);
      // kc0
      TR_ISSUE(tB, 1, bufo);
      BLOADR(bZ, wsb, 2)
      WAITLG(10);
      MFMA_SET(tA, bX0, bX1, bX2, bX3);
      // kc1
      TR_ISSUE(tA, 2, bufo);
      BLOADR(bX, wsb, 3)
      WAITLG(10);
      MFMA_SET(tB, bY0, bY1, bY2, bY3);
      // staging for sc+1 folded into the compute stream (targets other buffer;
      // its ds_writes drain at the next WAITLG(10) — ledger exact, DS-only)
      if (sc < 7) {
        STAGE_WRITE(sc + 1, nbufo);
      }
      if (sc < 6) {
        STAGE_LOAD(sc + 2);
      }
      // kc2
      TR_ISSUE(tB, 3, bufo);
      BLOADR(bY, wsb, 4)
      WAITLG(10);
      MFMA_SET(tA, bZ0, bZ1, bZ2, bZ3);
      // kc3
      TR_ISSUE(tA, 4, bufo);
      WAITLG(10);
      MFMA_SET(tB, bX0, bX1, bX2, bX3);
      // prefetch next sc's kc0 B while kc4 computes
      BLOADR(bX, wsbn, 0)
      // kc4
      WAITLG(0);
      MFMA_SET(tA, bY0, bY1, bY2, bY3);
      BLOADR(bY, wsbn, 1)
    } else {
      // fallback: registers from fp32 weights (slow but correct)
      const float* q0 = wgt + (size_t)coB_ * 1152 + sc * 144 + g * 8;
      const float* q1 = q0 + (size_t)16 * 1152;
      const float* q2 = q0 + (size_t)32 * 1152;
      const float* q3 = q0 + (size_t)48 * 1152;
      if (sc < 7) {
        STAGE_WRITE(sc + 1, nbufo);
      }
      if (sc < 6) {
        STAGE_LOAD(sc + 2);
      }
#pragma unroll
      for (int kc = 0; kc < 5; ++kc) {
        short8 c0 = load_bq(q0, kc, g), c1 = load_bq(q1, kc, g);
        short8 c2 = load_bq(q2, kc, g), c3 = load_bq(q3, kc, g);
        TR_ISSUE(tA, kc, bufo);
        WAITLG(0);
        MFMA_SET(tA, c0, c1, c2, c3);
      }
    }

    __syncthreads();
  }

  // ---- epilogue: C frag col(co)=l15, row(m)=g*4+r ----
  float bv0 = bias[coB_];
  float bv1 = bias[coB_ + 16];
  float bv2 = bias[coB_ + 32];
  float bv3 = bias[coB_ + 48];
  size_t ob0 = (((size_t)b * COUT + coB_) * HOUT + oh) * WOUT;
  size_t ob1 = ob0 + (size_t)16 * HOUT * WOUT;
  size_t ob2 = ob0 + (size_t)32 * HOUT * WOUT;
  size_t ob3 = ob0 + (size_t)48 * HOUT * WOUT;
#pragma unroll
  for (int mf = 0; mf < 5; ++mf) {
    int owb = mf * 16 + g * 4;
#pragma unroll
    for (int r = 0; r < 4; ++r) {
      int ow = owb + r;
      if (ow < WOUT) {
        out[ob0 + ow] = acc[mf][0][r] + bv0;
        out[ob1 + ow] = acc[mf][1][r] + bv1;
        out[ob2 + ow] = acc[mf][2][r] + bv2;
        out[ob3 + ow] = acc[mf][3][r] + bv3;
      }
    }
  }
}

extern "C" void kernel_launch(void* const* d_in, const int* in_sizes, int n_in,
                              void* d_out, int out_size, void* d_ws, size_t ws_size,
                              hipStream_t stream) {
  const float* x    = (const float*)d_in[0];
  const float* wgt  = (const float*)d_in[1];
  const float* bias = (const float*)d_in[2];
  float* out        = (float*)d_out;

  dim3 grid(16 * 112);
  dim3 block(THREADS);

  if (ws_size >= WS_NEED) {
    wprep<<<dim3(WS_SH8 / 256), dim3(256), 0, stream>>>(wgt, (uint4*)d_ws);
    conv_mfma<1><<<grid, block, 0, stream>>>(x, wgt, (const short8*)d_ws, bias, out);
  } else {
    conv_mfma<0><<<grid, block, 0, stream>>>(x, wgt, (const short8*)d_ws, bias, out);
  }
}

// Round 14
// 199.845 us; speedup vs baseline: 1.6143x; 1.6143x over previous
//
#include <hip/hip_runtime.h>
#include <cstdint>

constexpr int B_   = 16;
constexpr int CIN  = 128;
constexpr int H_   = 224;
constexpr int W_   = 224;
constexpr int COUT = 256;
constexpr int HOUT = 112;
constexpr int WOUT = 75;

constexpr int CI_SC = 16;     // input channels per super-chunk
constexpr int KSC_R = 144;    // real k per super-chunk
constexpr int KP    = 160;    // padded k per super-chunk (5 x K=32)
constexpr int NSC   = 8;
constexpr int THREADS = 256;  // 4 waves: 4 co-groups of 64

constexpr int WS_SH8  = COUT * KP * NSC / 8;       // 40960 short8 slots
constexpr size_t WS_NEED = (size_t)WS_SH8 * 16;    // 655360 B

// LDS map: A tile [0, 25600); B ring 3 x 16384 at 25600
constexpr int B_OFF   = 25600;
constexpr int LDS_TOT = B_OFF + 3 * 16384;         // 74752

typedef float  f32x4   __attribute__((ext_vector_type(4)));
typedef short  short8  __attribute__((ext_vector_type(8)));
typedef unsigned int uint32x4 __attribute__((ext_vector_type(4)));

struct U64x2 { unsigned long long lo, hi; };
__device__ inline short8 bc8(unsigned long long a, unsigned long long b) {
  U64x2 u{a, b};
  return __builtin_bit_cast(short8, u);
}
__device__ inline short8 cv8(uint32x4 v) { return __builtin_bit_cast(short8, v); }

__device__ inline unsigned cvtpk(float a, float b) {
  unsigned r;
  asm("v_cvt_pk_bf16_f32 %0, %1, %2" : "=v"(r) : "v"(a), "v"(b));
  return r;  // lo16 = bf16(a), hi16 = bf16(b)
}

__device__ __forceinline__ void gload_lds(const void* g, void* l) {
  __builtin_amdgcn_global_load_lds((const __attribute__((address_space(1))) void*)g,
                                   (__attribute__((address_space(3))) void*)l, 16, 0, 0);
}

// ---- prepass: fp32 weights -> bf16, layout [sc][kc][g][co][8k] (coalesced B frags) ----
__global__ __launch_bounds__(256) void wprep(const float* __restrict__ wgt,
                                             uint4* __restrict__ ws) {
  int o  = blockIdx.x * 256 + threadIdx.x;   // 40960 short8 outputs
  int co = o & 255;
  int t  = o >> 8;          // 0..159
  int g  = t & 3;
  int u  = t >> 2;          // 0..39
  int kc = u % 5;
  int sc = u / 5;
  int kloc = kc * 32 + g * 8;                // k within super-chunk
  float f[8];
  if (kloc < KSC_R) {
    const float* p = wgt + (size_t)co * 1152 + sc * KSC_R + kloc;  // 8-aligned
    float4 a = *(const float4*)p;
    float4 b = *(const float4*)(p + 4);
    f[0] = a.x; f[1] = a.y; f[2] = a.z; f[3] = a.w;
    f[4] = b.x; f[5] = b.y; f[6] = b.z; f[7] = b.w;
  } else {
#pragma unroll
    for (int e = 0; e < 8; ++e) f[e] = 0.f;
  }
  ws[o] = uint4{cvtpk(f[0], f[1]), cvtpk(f[2], f[3]), cvtpk(f[4], f[5]), cvtpk(f[6], f[7])};
}

// fallback (no ws): convert from fp32 weights in-flight (uncoalesced, slow but correct)
__device__ __forceinline__ short8 load_bq(const float* q, int kc, int g) {
  if (kc == 4 && g >= 2) return short8{};
  const float* s = q + kc * 32;
  float4 x0 = *(const float4*)s, x1 = *(const float4*)(s + 4);
  uint4 u{cvtpk(x0.x, x0.y), cvtpk(x0.z, x0.w), cvtpk(x1.x, x1.y), cvtpk(x1.z, x1.w)};
  return __builtin_bit_cast(short8, u);
}

// 10 tr reads for one K=32 chunk (5 m-frags x 2 k-halves); A row (4k x 80m) = 640B
#define TR_ISSUE(S, KC)                                                                   \
  {                                                                                       \
    unsigned a_ = abase + (unsigned)((KC) * 5120);                                        \
    asm volatile("ds_read_b64_tr_b16 %0, %1"             : "=v"(S##0) : "v"(a_));         \
    asm volatile("ds_read_b64_tr_b16 %0, %1 offset:640"  : "=v"(S##1) : "v"(a_));         \
    asm volatile("ds_read_b64_tr_b16 %0, %1 offset:128"  : "=v"(S##2) : "v"(a_));         \
    asm volatile("ds_read_b64_tr_b16 %0, %1 offset:768"  : "=v"(S##3) : "v"(a_));         \
    asm volatile("ds_read_b64_tr_b16 %0, %1 offset:256"  : "=v"(S##4) : "v"(a_));         \
    asm volatile("ds_read_b64_tr_b16 %0, %1 offset:896"  : "=v"(S##5) : "v"(a_));         \
    asm volatile("ds_read_b64_tr_b16 %0, %1 offset:384"  : "=v"(S##6) : "v"(a_));         \
    asm volatile("ds_read_b64_tr_b16 %0, %1 offset:1024" : "=v"(S##7) : "v"(a_));         \
    asm volatile("ds_read_b64_tr_b16 %0, %1 offset:512"  : "=v"(S##8) : "v"(a_));         \
    asm volatile("ds_read_b64_tr_b16 %0, %1 offset:1152" : "=v"(S##9) : "v"(a_));         \
  }

// 4 x ds_read_b128 of the wave-private B slice (lane-contiguous 1KB per frag)
#define B_ISSUE(BR, BB)                                                                   \
  asm volatile("ds_read_b128 %0, %1"             : "=v"(BR##0) : "v"(BB));                \
  asm volatile("ds_read_b128 %0, %1 offset:1024" : "=v"(BR##1) : "v"(BB));                \
  asm volatile("ds_read_b128 %0, %1 offset:2048" : "=v"(BR##2) : "v"(BB));                \
  asm volatile("ds_read_b128 %0, %1 offset:3072" : "=v"(BR##3) : "v"(BB));

// DMA one kc's wave-private B slice (4 KB) from ws into LDS buf BS
#define B_DMA(GT, BS)                                                                     \
  {                                                                                       \
    const char* s_ = wsl + (size_t)(GT) * 16384;                                          \
    char* d_ = bD + (BS) * 16384;                                                         \
    gload_lds(s_,       d_);                                                              \
    gload_lds(s_ + 256, d_ + 1024);                                                       \
    gload_lds(s_ + 512, d_ + 2048);                                                       \
    gload_lds(s_ + 768, d_ + 3072);                                                       \
  }

#define VMGATE(N)                                                                         \
  asm volatile("s_waitcnt vmcnt(" #N ")" ::: "memory");                                   \
  __builtin_amdgcn_sched_barrier(0);

#define WAITLG(N)                                                                         \
  asm volatile("s_waitcnt lgkmcnt(" #N ")" ::: "memory");                                 \
  __builtin_amdgcn_sched_barrier(0);

// 5 A-frags x 4 B-frags = 20 MFMAs
#define MFMA_SET(S, B0, B1, B2, B3)                                                       \
  {                                                                                       \
    short8 a0_ = bc8(S##0, S##1);                                                         \
    short8 a1_ = bc8(S##2, S##3);                                                         \
    short8 a2_ = bc8(S##4, S##5);                                                         \
    short8 a3_ = bc8(S##6, S##7);                                                         \
    short8 a4_ = bc8(S##8, S##9);                                                         \
    __builtin_amdgcn_s_setprio(1);                                                        \
    acc[0][0] = __builtin_amdgcn_mfma_f32_16x16x32_bf16(a0_, B0, acc[0][0], 0, 0, 0);     \
    acc[0][1] = __builtin_amdgcn_mfma_f32_16x16x32_bf16(a0_, B1, acc[0][1], 0, 0, 0);     \
    acc[0][2] = __builtin_amdgcn_mfma_f32_16x16x32_bf16(a0_, B2, acc[0][2], 0, 0, 0);     \
    acc[0][3] = __builtin_amdgcn_mfma_f32_16x16x32_bf16(a0_, B3, acc[0][3], 0, 0, 0);     \
    acc[1][0] = __builtin_amdgcn_mfma_f32_16x16x32_bf16(a1_, B0, acc[1][0], 0, 0, 0);     \
    acc[1][1] = __builtin_amdgcn_mfma_f32_16x16x32_bf16(a1_, B1, acc[1][1], 0, 0, 0);     \
    acc[1][2] = __builtin_amdgcn_mfma_f32_16x16x32_bf16(a1_, B2, acc[1][2], 0, 0, 0);     \
    acc[1][3] = __builtin_amdgcn_mfma_f32_16x16x32_bf16(a1_, B3, acc[1][3], 0, 0, 0);     \
    acc[2][0] = __builtin_amdgcn_mfma_f32_16x16x32_bf16(a2_, B0, acc[2][0], 0, 0, 0);     \
    acc[2][1] = __builtin_amdgcn_mfma_f32_16x16x32_bf16(a2_, B1, acc[2][1], 0, 0, 0);     \
    acc[2][2] = __builtin_amdgcn_mfma_f32_16x16x32_bf16(a2_, B2, acc[2][2], 0, 0, 0);     \
    acc[2][3] = __builtin_amdgcn_mfma_f32_16x16x32_bf16(a2_, B3, acc[2][3], 0, 0, 0);     \
    acc[3][0] = __builtin_amdgcn_mfma_f32_16x16x32_bf16(a3_, B0, acc[3][0], 0, 0, 0);     \
    acc[3][1] = __builtin_amdgcn_mfma_f32_16x16x32_bf16(a3_, B1, acc[3][1], 0, 0, 0);     \
    acc[3][2] = __builtin_amdgcn_mfma_f32_16x16x32_bf16(a3_, B2, acc[3][2], 0, 0, 0);     \
    acc[3][3] = __builtin_amdgcn_mfma_f32_16x16x32_bf16(a3_, B3, acc[3][3], 0, 0, 0);     \
    acc[4][0] = __builtin_amdgcn_mfma_f32_16x16x32_bf16(a4_, B0, acc[4][0], 0, 0, 0);     \
    acc[4][1] = __builtin_amdgcn_mfma_f32_16x16x32_bf16(a4_, B1, acc[4][1], 0, 0, 0);     \
    acc[4][2] = __builtin_amdgcn_mfma_f32_16x16x32_bf16(a4_, B2, acc[4][2], 0, 0, 0);     \
    acc[4][3] = __builtin_amdgcn_mfma_f32_16x16x32_bf16(a4_, B3, acc[4][3], 0, 0, 0);     \
    __builtin_amdgcn_s_setprio(0);                                                        \
  }

template <int WS>
__global__ __launch_bounds__(THREADS, 2) void conv_mfma(
    const float* __restrict__ x, const float* __restrict__ wgt,
    const short8* __restrict__ wbf, const float* __restrict__ bias,
    float* __restrict__ out) {

  // A tile: [KP=160 k][80 m] bf16, [4k x 16m] subtiles:
  // byte(k,m) = ((k>>2)*5 + (m>>4))*128 + (k&3)*32 + (m&15)*2
  __shared__ __align__(16) unsigned char smem[LDS_TOT];

  // XCD-chunked bijective swizzle: 1792 blocks = 8 XCDs * 224
  int Lid = (blockIdx.x & 7) * 224 + (blockIdx.x >> 3);
  int oh  = Lid % 112;
  int b   = Lid / 112;

  const int tid   = threadIdx.x;
  const int lane  = tid & 63;
  const int cogrp = tid >> 6;         // wave id = co-group of 64
  const int g     = lane >> 4;        // k-lane-group
  const int l15   = lane & 15;

  const float* xb = x + (size_t)b * CIN * H_ * W_;
  const int coB_  = cogrp * 64 + l15;

  const unsigned sbase = (unsigned)(uintptr_t)&smem[0];
  const unsigned abase = sbase + (unsigned)(g * 1280 + l15 * 8);
  const unsigned vB    = sbase + (unsigned)(B_OFF + cogrp * 4096 + lane * 16);
  char* bD = (char*)&smem[B_OFF + cogrp * 4096];                 // DMA dest (wave-uniform)
  const char* wsl = (const char*)wbf + (size_t)(g * 4096 + cogrp * 1024 + l15 * 16);

  // NaN fix: zero never-staged A k-rows 144..159 (contiguous 2560 B @23040).
  if (tid < 160) {
    *reinterpret_cast<uint4*>(&smem[23040 + tid * 16]) = uint4{0u, 0u, 0u, 0u};
  }

  f32x4 acc[5][4];
#pragma unroll
  for (int mf = 0; mf < 5; ++mf)
#pragma unroll
    for (int cf = 0; cf < 4; ++cf)
#pragma unroll
      for (int i = 0; i < 4; ++i) acc[mf][cf][i] = 0.f;

  unsigned long long tA0, tA1, tA2, tA3, tA4, tA5, tA6, tA7, tA8, tA9;
  unsigned long long tB0, tB1, tB2, tB3, tB4, tB5, tB6, tB7, tB8, tB9;
  uint32x4 brA0, brA1, brA2, brA3, brB0, brB1, brB2, brB3;

  int bsel = 0, gkc = 0, gt;
  unsigned bb;
  if (WS) { B_DMA(0, 0) B_DMA(1, 1) B_DMA(2, 2) }   // prime the ring

  for (int sc = 0; sc < NSC; ++sc) {
    if (sc) __syncthreads();

    // ---- stage A: 912 items = 16ci x 3kh x 19 ow-groups, coalesced fp32 loads ----
    const float* xs = xb + (size_t)sc * (CI_SC * H_ * W_);
#pragma unroll
    for (int j = 0; j < 4; ++j) {
      int it = tid + THREADS * j;
      if (j < 3 || it < 912) {
        int gg  = it % 19;
        int rid = it / 19;
        int ci  = rid & 15;
        int kh  = rid >> 4;
        int ih  = 2 * oh - 1 + kh;
        bool rowok = (unsigned)ih < (unsigned)H_;
        int ro  = (ci * H_ + (rowok ? ih : 0)) * W_;
        int iwb = 12 * gg;
        unsigned mAj = rowok ? 0xFFFFFFFFu : 0u;
        unsigned mFj = mAj & (gg ? 0xFFFFFFFFu : 0xFFFF0000u);

        const float* ap = xs + (ro + iwb);
        float4 a4 = *(const float4*)ap;
        float4 b4 = *(const float4*)(ap + 4);
        float4 c4 = *(const float4*)(xs + (ro + (iwb + 8 > 220 ? 220 : iwb + 8)));
        float fm1 = xs[ro + iwb - (gg ? 1 : 0)];

        int k = ci * 9 + kh * 3;
        int m = 4 * gg;
        unsigned base = (unsigned)(((k >> 2) * 5 + (m >> 4)) * 128 + (m & 15) * 2);
        unsigned o0 = base + (unsigned)((k & 3) * 32);
        unsigned o1 = base + (unsigned)(((k + 1) & 3) * 32) + (((k + 1) >> 2) - (k >> 2)) * 640u;
        unsigned o2 = base + (unsigned)(((k + 2) & 3) * 32) + (((k + 2) >> 2) - (k >> 2)) * 640u;

        unsigned l0 = cvtpk(fm1,  a4.z) & mFj;
        unsigned h0 = cvtpk(b4.y, c4.x) & mAj;
        unsigned l1 = cvtpk(a4.x, a4.w) & mAj;
        unsigned h1 = cvtpk(b4.z, c4.y) & mAj;
        unsigned l2 = cvtpk(a4.y, b4.x) & mAj;
        unsigned h2 = cvtpk(b4.w, c4.z) & mAj;
        *(uint2*)&smem[o0] = make_uint2(l0, h0);
        *(uint2*)&smem[o1] = make_uint2(l1, h1);
        *(uint2*)&smem[o2] = make_uint2(l2, h2);
      }
    }
    __syncthreads();

    if (WS) {
      const int b1 = bsel + 1 == 3 ? 0 : bsel + 1;
      const int b2 = b1 + 1 == 3 ? 0 : b1 + 1;

      // sc-prologue: set kc0 -> (tA, brA) from buf bsel
      VMGATE(8);
      bb = vB + (unsigned)bsel * 16384u;
      B_ISSUE(brA, bb);
      TR_ISSUE(tA, 0);

      // k0: issue kc1 -> (tB, brB, b1); compute kc0
      VMGATE(4);
      bb = vB + (unsigned)b1 * 16384u;
      B_ISSUE(brB, bb);
      TR_ISSUE(tB, 1);
      WAITLG(14);
      { short8 c0 = cv8(brA0), c1 = cv8(brA1), c2 = cv8(brA2), c3 = cv8(brA3);
        MFMA_SET(tA, c0, c1, c2, c3); }
      gt = gkc + 3; if (gt > 39) gt = 39;
      B_DMA(gt, bsel);
      ++gkc;

      // k1: issue kc2 -> (tA, brA, b2); compute kc1
      VMGATE(4);
      bb = vB + (unsigned)b2 * 16384u;
      B_ISSUE(brA, bb);
      TR_ISSUE(tA, 2);
      WAITLG(14);
      { short8 c0 = cv8(brB0), c1 = cv8(brB1), c2 = cv8(brB2), c3 = cv8(brB3);
        MFMA_SET(tB, c0, c1, c2, c3); }
      gt = gkc + 3; if (gt > 39) gt = 39;
      B_DMA(gt, b1);
      ++gkc;

      // k2: issue kc3 -> (tB, brB, bsel); compute kc2
      VMGATE(4);
      bb = vB + (unsigned)bsel * 16384u;
      B_ISSUE(brB, bb);
      TR_ISSUE(tB, 3);
      WAITLG(14);
      { short8 c0 = cv8(brA0), c1 = cv8(brA1), c2 = cv8(brA2), c3 = cv8(brA3);
        MFMA_SET(tA, c0, c1, c2, c3); }
      gt = gkc + 3; if (gt > 39) gt = 39;
      B_DMA(gt, b2);
      ++gkc;

      // k3: issue kc4 -> (tA, brA, b1); compute kc3
      VMGATE(4);
      bb = vB + (unsigned)b1 * 16384u;
      B_ISSUE(brA, bb);
      TR_ISSUE(tA, 4);
      WAITLG(14);
      { short8 c0 = cv8(brB0), c1 = cv8(brB1), c2 = cv8(brB2), c3 = cv8(brB3);
        MFMA_SET(tB, c0, c1, c2, c3); }
      gt = gkc + 3; if (gt > 39) gt = 39;
      B_DMA(gt, bsel);
      ++gkc;

      // k4: compute kc4
      WAITLG(0);
      { short8 c0 = cv8(brA0), c1 = cv8(brA1), c2 = cv8(brA2), c3 = cv8(brA3);
        MFMA_SET(tA, c0, c1, c2, c3); }
      gt = gkc + 3; if (gt > 39) gt = 39;
      B_DMA(gt, b1);
      ++gkc;

      bsel = b2;
    } else {
      // fallback: registers from fp32 weights (slow but correct)
      const float* q0 = wgt + (size_t)coB_ * 1152 + sc * 144 + g * 8;
      const float* q1 = q0 + (size_t)16 * 1152;
      const float* q2 = q0 + (size_t)32 * 1152;
      const float* q3 = q0 + (size_t)48 * 1152;
#pragma unroll
      for (int kc = 0; kc < 5; ++kc) {
        short8 c0 = load_bq(q0, kc, g), c1 = load_bq(q1, kc, g);
        short8 c2 = load_bq(q2, kc, g), c3 = load_bq(q3, kc, g);
        TR_ISSUE(tA, kc);
        WAITLG(0);
        MFMA_SET(tA, c0, c1, c2, c3);
      }
    }
  }

  asm volatile("s_waitcnt vmcnt(0)" ::: "memory");   // drain tail DMAs

  // ---- epilogue: C frag col(co)=l15, row(m)=g*4+r ----
  float bv0 = bias[coB_];
  float bv1 = bias[coB_ + 16];
  float bv2 = bias[coB_ + 32];
  float bv3 = bias[coB_ + 48];
  size_t ob0 = (((size_t)b * COUT + coB_) * HOUT + oh) * WOUT;
  size_t ob1 = ob0 + (size_t)16 * HOUT * WOUT;
  size_t ob2 = ob0 + (size_t)32 * HOUT * WOUT;
  size_t ob3 = ob0 + (size_t)48 * HOUT * WOUT;
#pragma unroll
  for (int mf = 0; mf < 5; ++mf) {
    int owb = mf * 16 + g * 4;
#pragma unroll
    for (int r = 0; r < 4; ++r) {
      int ow = owb + r;
      if (ow < WOUT) {
        out[ob0 + ow] = acc[mf][0][r] + bv0;
        out[ob1 + ow] = acc[mf][1][r] + bv1;
        out[ob2 + ow] = acc[mf][2][r] + bv2;
        out[ob3 + ow] = acc[mf][3][r] + bv3;
      }
    }
  }
}

extern "C" void kernel_launch(void* const* d_in, const int* in_sizes, int n_in,
                              void* d_out, int out_size, void* d_ws, size_t ws_size,
                              hipStream_t stream) {
  const float* x    = (const float*)d_in[0];
  const float* wgt  = (const float*)d_in[1];
  const float* bias = (const float*)d_in[2];
  float* out        = (float*)d_out;

  dim3 grid(16 * 112);
  dim3 block(THREADS);

  if (ws_size >= WS_NEED) {
    wprep<<<dim3(WS_SH8 / 256), dim3(256), 0, stream>>>(wgt, (uint4*)d_ws);
    conv_mfma<1><<<grid, block, 0, stream>>>(x, wgt, (const short8*)d_ws, bias, out);
  } else {
    conv_mfma<0><<<grid, block, 0, stream>>>(x, wgt, (const short8*)d_ws, bias, out);
  }
}